// Round 1
// baseline (616.613 us; speedup 1.0000x reference)
//
#include <hip/hip_runtime.h>

#define H    2048
#define NH   8
#define NKV  2
#define HD   256
#define DFF  4096
#define PLD  256
#define NL   8
#define WIN  512
#define FULLS 4096
#define EPS  1e-6f
#define ATT_SCALE 0.0625f          // 1/sqrt(256)
#define PLE_PROJ_SCALE 0.022097086912079608f  // 2048^-0.5
#define PLE_IN_SCALE   0.7071067811865476f    // 2^-0.5
#define MAXSPLIT 64

__device__ inline float waveSum(float v) {
#pragma unroll
  for (int o = 32; o; o >>= 1) v += __shfl_xor(v, o);
  return v;
}
__device__ inline float waveMax(float v) {
#pragma unroll
  for (int o = 32; o; o >>= 1) v = fmaxf(v, __shfl_xor(v, o));
  return v;
}
// block = 256 threads
__device__ inline float blockSum(float v) {
  __shared__ float red[4];
  int lane = threadIdx.x & 63, wid = threadIdx.x >> 6;
  v = waveSum(v);
  if (lane == 0) red[wid] = v;
  __syncthreads();
  float s = red[0] + red[1] + red[2] + red[3];
  __syncthreads();
  return s;
}

__device__ inline float gelu_t(float x) {
  float x3 = x * x * x;
  return 0.5f * x * (1.f + tanhf(0.79788456080286536f * (x + 0.044715f * x3)));
}

// ---------------- GEMV: y[row] = dot(W[row,:], x) * scale ----------------
__global__ __launch_bounds__(256) void k_gemv(const float* __restrict__ W,
                                              const float* __restrict__ x,
                                              float* __restrict__ y,
                                              int cols, float scale) {
  size_t row = blockIdx.x;
  const float* wr = W + row * (size_t)cols;
  float acc = 0.f;
  for (int c = threadIdx.x * 4; c < cols; c += 1024) {
    float4 w4 = *(const float4*)(wr + c);
    float4 x4 = *(const float4*)(x + c);
    acc = fmaf(w4.x, x4.x, fmaf(w4.y, x4.y, fmaf(w4.z, x4.z, fmaf(w4.w, x4.w, acc))));
  }
  float s = blockSum(acc);
  if (threadIdx.x == 0) y[row] = s * scale;
}

// ---------------- fused QKV GEMV (rows: 2048 q, 512 k, 512 v) ----------------
__global__ __launch_bounds__(256) void k_gemv_qkv(const float* __restrict__ Wq,
                                                  const float* __restrict__ Wk,
                                                  const float* __restrict__ Wv,
                                                  const float* __restrict__ x,
                                                  float* __restrict__ y) {
  int row = blockIdx.x;
  const float* wr;
  if (row < 2048)      wr = Wq + (size_t)row * H;
  else if (row < 2560) wr = Wk + (size_t)(row - 2048) * H;
  else                 wr = Wv + (size_t)(row - 2560) * H;
  float acc = 0.f;
  for (int c = threadIdx.x * 4; c < H; c += 1024) {
    float4 w4 = *(const float4*)(wr + c);
    float4 x4 = *(const float4*)(x + c);
    acc = fmaf(w4.x, x4.x, fmaf(w4.y, x4.y, fmaf(w4.z, x4.z, fmaf(w4.w, x4.w, acc))));
  }
  float s = blockSum(acc);
  if (threadIdx.x == 0) y[row] = s;
}

// ---------------- fused gate/up GEMV + gelu*up epilogue ----------------
__global__ __launch_bounds__(256) void k_gateup(const float* __restrict__ Wg,
                                                const float* __restrict__ Wu,
                                                const float* __restrict__ x,
                                                float* __restrict__ act) {
  size_t row = blockIdx.x;
  const float* g = Wg + row * H;
  const float* u = Wu + row * H;
  float ag = 0.f, au = 0.f;
  for (int c = threadIdx.x * 4; c < H; c += 1024) {
    float4 x4 = *(const float4*)(x + c);
    float4 g4 = *(const float4*)(g + c);
    float4 u4 = *(const float4*)(u + c);
    ag = fmaf(g4.x, x4.x, fmaf(g4.y, x4.y, fmaf(g4.z, x4.z, fmaf(g4.w, x4.w, ag))));
    au = fmaf(u4.x, x4.x, fmaf(u4.y, x4.y, fmaf(u4.z, x4.z, fmaf(u4.w, x4.w, au))));
  }
  __shared__ float red[8];
  int lane = threadIdx.x & 63, wid = threadIdx.x >> 6;
  ag = waveSum(ag); au = waveSum(au);
  if (lane == 0) { red[wid] = ag; red[4 + wid] = au; }
  __syncthreads();
  if (threadIdx.x == 0) {
    float sg = red[0] + red[1] + red[2] + red[3];
    float su = red[4] + red[5] + red[6] + red[7];
    act[row] = gelu_t(sg) * su;
  }
}

// ---------------- PL gate GEMV + gelu*sl epilogue (256 rows) ----------------
__global__ __launch_bounds__(256) void k_plgate(const float* __restrict__ W,
                                                const float* __restrict__ x,
                                                const float* __restrict__ sl,
                                                float* __restrict__ gated) {
  size_t row = blockIdx.x;
  const float* wr = W + row * H;
  float acc = 0.f;
  for (int c = threadIdx.x * 4; c < H; c += 1024) {
    float4 w4 = *(const float4*)(wr + c);
    float4 x4 = *(const float4*)(x + c);
    acc = fmaf(w4.x, x4.x, fmaf(w4.y, x4.y, fmaf(w4.z, x4.z, fmaf(w4.w, x4.w, acc))));
  }
  float s = blockSum(acc);
  if (threadIdx.x == 0) gated[row] = gelu_t(s) * sl[row];
}

// ---------------- y = x * rsqrt(mean(x^2)+eps) * w   (N=2048, 1 block) -----
__global__ __launch_bounds__(256) void k_rms(const float* __restrict__ x,
                                             const float* __restrict__ w,
                                             float* __restrict__ y) {
  float v[8]; float ss = 0.f;
#pragma unroll
  for (int k = 0; k < 8; k++) { v[k] = x[threadIdx.x + 256 * k]; ss += v[k] * v[k]; }
  float s = blockSum(ss);
  float r = rsqrtf(s * (1.f / 2048.f) + EPS);
#pragma unroll
  for (int k = 0; k < 8; k++) {
    int idx = threadIdx.x + 256 * k;
    y[idx] = v[k] * r * w[idx];
  }
}

// -------- hs = (hs + rms(x)*w) * (scal ? scal[li] : 1)   (N=2048, 1 block) --
__global__ __launch_bounds__(256) void k_add_rms(float* __restrict__ hs,
                                                 const float* __restrict__ x,
                                                 const float* __restrict__ w,
                                                 const float* __restrict__ scal,
                                                 int li) {
  float v[8]; float ss = 0.f;
#pragma unroll
  for (int k = 0; k < 8; k++) { v[k] = x[threadIdx.x + 256 * k]; ss += v[k] * v[k]; }
  float s = blockSum(ss);
  float r = rsqrtf(s * (1.f / 2048.f) + EPS);
  float sc = scal ? scal[li] : 1.f;
#pragma unroll
  for (int k = 0; k < 8; k++) {
    int idx = threadIdx.x + 256 * k;
    hs[idx] = (hs[idx] + v[k] * r * w[idx]) * sc;
  }
}

// ------------- q/k rms+rope, v vnorm. grid=12 blocks of 256 -----------------
__global__ __launch_bounds__(256) void k_qknorm(float* __restrict__ qkv,
                                                const float* __restrict__ qw,
                                                const float* __restrict__ kw,
                                                const float* __restrict__ cosp,
                                                const float* __restrict__ sinp) {
  int b = blockIdx.x, t = threadIdx.x;
  float* p; const float* w; bool rope = true;
  if (b < 8)       { p = qkv + b * 256;              w = qw; }
  else if (b < 10) { p = qkv + 2048 + (b - 8) * 256; w = kw; }
  else             { p = qkv + 2560 + (b - 10) * 256; w = nullptr; rope = false; }
  float v = p[t];
  float s = blockSum(v * v);
  float r = rsqrtf(s * (1.f / 256.f) + EPS);
  float xn = v * r * (w ? w[t] : 1.f);
  __shared__ float lds[256];
  lds[t] = xn;
  __syncthreads();
  float out = xn;
  if (rope) {
    float rot = (t < 128) ? -lds[t + 128] : lds[t - 128];
    out = xn * cosp[t] + rot * sinp[t];
  }
  p[t] = out;
}

// -------- sliding cache: out[:, j] = j<511 ? in[:, j+1] : new ---------------
// 2 (K,V) * 2 kv * 512 j * 64 float4 = 131072 float4 -> 512 blocks
__global__ __launch_bounds__(256) void k_cache_slide(const float* __restrict__ Kin,
                                                     const float* __restrict__ Vin,
                                                     const float* __restrict__ kn,
                                                     const float* __restrict__ vn,
                                                     float* __restrict__ Ko,
                                                     float* __restrict__ Vo) {
  int gi = blockIdx.x * 256 + threadIdx.x;
  int sel = gi >> 16;
  int rem = gi & 65535;
  int kv  = rem >> 15;
  int r2  = rem & 32767;
  int j   = r2 >> 6;
  int d4  = r2 & 63;
  const float4* in4 = (const float4*)(sel ? Vin : Kin);
  const float4* nn4 = (const float4*)(sel ? vn : kn);
  float4*       o4  = (float4*)(sel ? Vo : Ko);
  float4 v = (j < 511) ? in4[(kv * 512 + j + 1) * 64 + d4] : nn4[kv * 64 + d4];
  o4[(kv * 512 + j) * 64 + d4] = v;
}

// -------- full cache: out = old*(1-m) + new*m ---------------
// 2 (K,V) * 2 kv * 4096 j * 64 float4 = 1048576 float4 -> 4096 blocks
__global__ __launch_bounds__(256) void k_cache_full(const float* __restrict__ Kin,
                                                    const float* __restrict__ Vin,
                                                    const float* __restrict__ kn,
                                                    const float* __restrict__ vn,
                                                    const float* __restrict__ um,
                                                    float* __restrict__ Ko,
                                                    float* __restrict__ Vo) {
  int gi = blockIdx.x * 256 + threadIdx.x;
  int sel = gi >> 19;
  int rem = gi & 524287;
  int kv  = rem >> 18;
  int r2  = rem & 262143;
  int j   = r2 >> 6;
  int d4  = r2 & 63;
  float m = um[j];
  const float4* in4 = (const float4*)(sel ? Vin : Kin);
  float4*       o4  = (float4*)(sel ? Vo : Ko);
  float4 v = in4[(kv * 4096 + j) * 64 + d4];
  if (m != 0.f) {
    const float4* nn4 = (const float4*)(sel ? vn : kn);
    float4 nv = nn4[kv * 64 + d4];
    float om = 1.f - m;
    v.x = v.x * om + nv.x * m;
    v.y = v.y * om + nv.y * m;
    v.z = v.z * om + nv.z * m;
    v.w = v.w * om + nv.w * m;
  }
  o4[(kv * 4096 + j) * 64 + d4] = v;
}

// -------- flash-decode partial: grid (nsplit, NH), C=64 positions/split -----
__global__ __launch_bounds__(256) void k_attn_partial(const float* __restrict__ q,
                                                      const float* __restrict__ K,
                                                      const float* __restrict__ V,
                                                      const float* __restrict__ mask,
                                                      float* __restrict__ part_o,
                                                      float* __restrict__ part_ml,
                                                      int S) {
  const int split = blockIdx.x, h = blockIdx.y;
  const int C = 64;
  const int kv = h >> 2;               // NREP = 4
  const int j0 = split * C;
  const int lane = threadIdx.x & 63, wid = threadIdx.x >> 6;
  __shared__ float s_s[64];
  __shared__ float s_ml[2];

  float4 q4 = *(const float4*)(q + h * 256 + lane * 4);
  const float* Kb = K + ((size_t)kv * S + j0) * 256;
  for (int jl = wid; jl < C; jl += 4) {
    const float4 k4 = *(const float4*)(Kb + (size_t)jl * 256 + lane * 4);
    float p = q4.x * k4.x + q4.y * k4.y + q4.z * k4.z + q4.w * k4.w;
    p = waveSum(p);
    if (lane == 0) s_s[jl] = p * ATT_SCALE + mask[j0 + jl];
  }
  __syncthreads();
  if (wid == 0) {
    float v = s_s[lane];
    float m = waveMax(v);
    float e = expf(v - m);
    s_s[lane] = e;
    float l = waveSum(e);
    if (lane == 0) { s_ml[0] = m; s_ml[1] = l; }
  }
  __syncthreads();
  const int d = threadIdx.x;
  const float* Vb = V + ((size_t)kv * S + j0) * 256;
  float o = 0.f;
#pragma unroll 8
  for (int jl = 0; jl < C; jl++) o = fmaf(s_s[jl], Vb[(size_t)jl * 256 + d], o);
  part_o[((size_t)h * MAXSPLIT + split) * 256 + d] = o;
  if (threadIdx.x < 2) part_ml[(h * MAXSPLIT + split) * 2 + threadIdx.x] = s_ml[threadIdx.x];
}

// -------- combine partials: grid NH blocks ----------------------------------
__global__ __launch_bounds__(256) void k_attn_combine(const float* __restrict__ part_o,
                                                      const float* __restrict__ part_ml,
                                                      float* __restrict__ attn,
                                                      int nsplit) {
  int h = blockIdx.x, d = threadIdx.x;
  float M = -INFINITY;
  for (int s = 0; s < nsplit; s++) M = fmaxf(M, part_ml[(h * MAXSPLIT + s) * 2]);
  float L = 0.f, o = 0.f;
  for (int s = 0; s < nsplit; s++) {
    float m = part_ml[(h * MAXSPLIT + s) * 2];
    float l = part_ml[(h * MAXSPLIT + s) * 2 + 1];
    float f = expf(m - M);
    L += l * f;
    o = fmaf(part_o[((size_t)h * MAXSPLIT + s) * 256 + d], f, o);
  }
  attn[h * 256 + d] = o / L;
}

// -------- PLE chunk norm: grid 8 blocks, plc = (rms(proj)*w + raw)*scale ----
__global__ __launch_bounds__(256) void k_plc(const float* __restrict__ proj,
                                             const float* __restrict__ plw,
                                             const float* __restrict__ plr,
                                             float* __restrict__ plc) {
  int c = blockIdx.x, t = threadIdx.x;
  float v = proj[c * 256 + t];
  float s = blockSum(v * v);
  float r = rsqrtf(s * (1.f / 256.f) + EPS);
  float g = v * r * plw[t];
  plc[c * 256 + t] = (g + plr[c * 256 + t]) * PLE_IN_SCALE;
}

extern "C" void kernel_launch(void* const* d_in, const int* in_sizes, int n_in,
                              void* d_out, int out_size, void* d_ws, size_t ws_size,
                              hipStream_t stream) {
  const float* hidden     = (const float*)d_in[0];
  const float* mask_full  = (const float*)d_in[1];
  const float* mask_slide = (const float*)d_in[2];
  const float* um         = (const float*)d_in[3];
  const float* plr        = (const float*)d_in[4];
  const float* cos_s      = (const float*)d_in[5];
  const float* sin_s      = (const float*)d_in[6];
  const float* cos_f      = (const float*)d_in[7];
  const float* sin_f      = (const float*)d_in[8];
  const float* Ksl        = (const float*)d_in[9];
  const float* Vsl        = (const float*)d_in[10];
  const float* Kfu        = (const float*)d_in[11];
  const float* Vfu        = (const float*)d_in[12];
  const float* Wq         = (const float*)d_in[13];
  const float* Wk         = (const float*)d_in[14];
  const float* Wv         = (const float*)d_in[15];
  const float* Wo         = (const float*)d_in[16];
  const float* qnw        = (const float*)d_in[17];
  const float* knw        = (const float*)d_in[18];
  const float* lin        = (const float*)d_in[19];
  const float* lpa        = (const float*)d_in[20];
  const float* lpf        = (const float*)d_in[21];
  const float* lpff       = (const float*)d_in[22];
  const float* Wg         = (const float*)d_in[23];
  const float* Wu         = (const float*)d_in[24];
  const float* Wd         = (const float*)d_in[25];
  const float* Wpg        = (const float*)d_in[26];
  const float* Wpp        = (const float*)d_in[27];
  const float* lpl        = (const float*)d_in[28];
  const float* lsc        = (const float*)d_in[29];
  const float* Wple       = (const float*)d_in[30];
  const float* plw        = (const float*)d_in[31];

  float* out = (float*)d_out;
  float* ws  = (float*)d_ws;

  float* hs    = ws;            // 2048
  float* hbuf  = ws + 2048;     // 2048
  float* qkv   = ws + 4096;     // 3072 (q 2048, k 512, v 512)
  float* attn  = ws + 7168;     // 2048
  float* tmp   = ws + 9216;     // 2048
  float* act   = ws + 11264;    // 4096
  float* plc   = ws + 15360;    // 2048
  float* gated = ws + 17408;    // 256
  float* pml   = ws + 17664;    // 8*64*2 = 1024
  float* po    = ws + 18688;    // 8*64*256 = 131072
  float* proj  = ws + 149760;   // 2048

  const size_t KS_SZ = (size_t)7 * 2 * 512 * 256;   // 1,835,008
  const size_t KF_SZ = (size_t)2 * 4096 * 256;      // 2,097,152
  float* outKs = out + 2048;
  float* outVs = outKs + KS_SZ;
  float* outKf = outVs + KS_SZ;
  float* outVf = outKf + KF_SZ;

  // hs = hidden_states
  hipMemcpyAsync(hs, hidden, 2048 * sizeof(float), hipMemcpyDeviceToDevice, stream);

  // PLE: only the first NL*PLD = 2048 rows of W_ple are ever consumed
  k_gemv<<<2048, 256, 0, stream>>>(Wple, hidden, proj, H, PLE_PROJ_SCALE);
  k_plc<<<8, 256, 0, stream>>>(proj, plw, plr, plc);

  int si = 0;
  for (int i = 0; i < NL; i++) {
    const bool isf = (i % 5 == 4);
    const float* cosp = isf ? cos_f : cos_s;
    const float* sinp = isf ? sin_f : sin_s;

    // h = rms(hs, ln_in_w[i])
    k_rms<<<1, 256, 0, stream>>>(hs, lin + i * 2048, hbuf);

    // q,k,v
    k_gemv_qkv<<<3072, 256, 0, stream>>>(Wq + (size_t)i * 2048 * 2048,
                                         Wk + (size_t)i * 512 * 2048,
                                         Wv + (size_t)i * 512 * 2048, hbuf, qkv);
    // norms + rope
    k_qknorm<<<12, 256, 0, stream>>>(qkv, qnw + i * 256, knw + i * 256, cosp, sinp);

    // cache update -> d_out (attention reads from there)
    const float* Ko; const float* Vo; int S;
    if (isf) {
      S = FULLS;
      k_cache_full<<<4096, 256, 0, stream>>>(Kfu, Vfu, qkv + 2048, qkv + 2560, um,
                                             outKf, outVf);
      Ko = outKf; Vo = outVf;
    } else {
      S = WIN;
      float* ko = outKs + (size_t)si * 2 * 512 * 256;
      float* vo = outVs + (size_t)si * 2 * 512 * 256;
      k_cache_slide<<<512, 256, 0, stream>>>(Ksl + (size_t)si * 2 * 512 * 256,
                                             Vsl + (size_t)si * 2 * 512 * 256,
                                             qkv + 2048, qkv + 2560, ko, vo);
      Ko = ko; Vo = vo;
    }

    // attention (flash-decode split-K, 64 positions per split)
    int nsplit = S / 64;
    dim3 g(nsplit, NH);
    k_attn_partial<<<g, 256, 0, stream>>>(qkv, Ko, Vo,
                                          isf ? mask_full : mask_slide, po, pml, S);
    k_attn_combine<<<NH, 256, 0, stream>>>(po, pml, attn, nsplit);

    // Wo and residual add
    k_gemv<<<2048, 256, 0, stream>>>(Wo + (size_t)i * 2048 * 2048, attn, tmp, H, 1.f);
    k_add_rms<<<1, 256, 0, stream>>>(hs, tmp, lpa + i * 2048, nullptr, 0);

    // MLP
    k_rms<<<1, 256, 0, stream>>>(hs, lpf + i * 2048, hbuf);
    k_gateup<<<4096, 256, 0, stream>>>(Wg + (size_t)i * 4096 * 2048,
                                       Wu + (size_t)i * 4096 * 2048, hbuf, act);
    k_gemv<<<2048, 256, 0, stream>>>(Wd + (size_t)i * 2048 * 4096, act, tmp, DFF, 1.f);
    k_add_rms<<<1, 256, 0, stream>>>(hs, tmp, lpff + i * 2048, nullptr, 0);

    // per-layer embedding block
    k_plgate<<<256, 256, 0, stream>>>(Wpg + (size_t)i * 256 * 2048, hs,
                                      plc + i * 256, gated);
    k_gemv<<<2048, 256, 0, stream>>>(Wpp + (size_t)i * 2048 * 256, gated, tmp, PLD, 1.f);
    k_add_rms<<<1, 256, 0, stream>>>(hs, tmp, lpl + i * 2048, lsc, i);

    if (!isf) si++;
  }

  // final hidden state -> output 0
  hipMemcpyAsync(out, hs, 2048 * sizeof(float), hipMemcpyDeviceToDevice, stream);
}